// Round 12
// baseline (155.396 us; speedup 1.0000x reference)
//
#include <hip/hip_runtime.h>

// LoopHead: node MLP (32->64->32) then edge decoder (gather/concat -> 64 -> 1)
// Wire dtypes per the reference: fp32 tensors, int32 edge_index, fp32 out.
// R12 = R9 (proven best, 63us edge) + (a) grid 2048 (8 blocks/CU residency
// cap at VGPR<=64, LDS=0), (b) 32-bit offset arithmetic for gathers/eidx
// (max offset 3.2M << 2^32) to cut 64-bit address-math VALU chains.

typedef short bfrag4 __attribute__((ext_vector_type(4)));  // 4 bf16 (x16 frag)
typedef short s16x8  __attribute__((ext_vector_type(8)));  // 8 bf16 (x32 frag)
typedef float f32x4v __attribute__((ext_vector_type(4)));  // fp32 x4

#define N_NODES 100000
#define N_EDGES 3200000

__device__ __forceinline__ unsigned short f2bf(float f) {
    unsigned int i = __float_as_uint(f);
    unsigned int r = i + 0x7FFFu + ((i >> 16) & 1u);  // RNE
    return (unsigned short)(r >> 16);
}

__device__ __forceinline__ bfrag4 cvt4(float x0, float x1, float x2, float x3) {
    bfrag4 v;
    v[0] = (short)f2bf(x0);
    v[1] = (short)f2bf(x1);
    v[2] = (short)f2bf(x2);
    v[3] = (short)f2bf(x3);
    return v;
}

// ---------------- Kernel 1: node projection -> z_loop (bf16 [N,32]) --------
// (verbatim round-3/6/7/9 version — proven through all harness checks)
__global__ __launch_bounds__(256) void node_proj_kernel(
    const float* __restrict__ z_mod,   // [N,32] fp32
    const float* __restrict__ w1,      // [32,64] row-major (k,n)
    const float* __restrict__ b1,      // [64]
    const float* __restrict__ w2,      // [64,32] row-major (k,n)
    const float* __restrict__ b2,      // [32]
    unsigned short* __restrict__ z_loop)  // [N,32] bf16 out (workspace)
{
    __shared__ unsigned short hbuf[4][16 * 72];

    const int tid  = threadIdx.x;
    const int wave = tid >> 6;
    const int lane = tid & 63;
    const int quad = lane >> 4;
    const int col  = lane & 15;

    bfrag4 bw1[2][4];   // stage 1: K=32 (2 steps), N=64 (4 n-tiles)
    float  bias1[4];
    for (int t = 0; t < 4; ++t) {
        const int n = col + 16 * t;
        for (int s = 0; s < 2; ++s)
            for (int j = 0; j < 4; ++j)
                bw1[s][t][j] = (short)f2bf(w1[(s * 16 + quad * 4 + j) * 64 + n]);
        bias1[t] = b1[n];
    }
    bfrag4 bw2[4][2];   // stage 2: K=64 (4 steps), N=32 (2 n-tiles)
    float  bias2[2];
    for (int t = 0; t < 2; ++t) {
        const int n = col + 16 * t;
        for (int s = 0; s < 4; ++s)
            for (int j = 0; j < 4; ++j)
                bw2[s][t][j] = (short)f2bf(w2[(s * 16 + quad * 4 + j) * 32 + n]);
        bias2[t] = b2[n];
    }

    unsigned short* hrow = &hbuf[wave][0];

    const int gwave  = blockIdx.x * 4 + wave;
    const int nwaves = gridDim.x * 4;
    const int ntiles = N_NODES / 16;   // 6250, exact

    for (int tile = gwave; tile < ntiles; tile += nwaves) {
        const int node0 = tile * 16;
        const float* zrow = z_mod + (size_t)(node0 + col) * 32;

        f32x4v za0 = *(const f32x4v*)(zrow + 0 * 16 + quad * 4);
        f32x4v za1 = *(const f32x4v*)(zrow + 1 * 16 + quad * 4);
        bfrag4 a10 = cvt4(za0[0], za0[1], za0[2], za0[3]);
        bfrag4 a11 = cvt4(za1[0], za1[1], za1[2], za1[3]);

        f32x4v acc[4];
        for (int t = 0; t < 4; ++t) {
            f32x4v c = {bias1[t], bias1[t], bias1[t], bias1[t]};
            c = __builtin_amdgcn_mfma_f32_16x16x16bf16_1k(a10, bw1[0][t], c, 0, 0, 0);
            c = __builtin_amdgcn_mfma_f32_16x16x16bf16_1k(a11, bw1[1][t], c, 0, 0, 0);
            acc[t] = c;
        }

        for (int t = 0; t < 4; ++t)
            for (int r = 0; r < 4; ++r) {
                float v = acc[t][r];
                v = v > 0.f ? v : 0.f;
                hrow[(quad * 4 + r) * 72 + (col + 16 * t)] = f2bf(v);
            }
        asm volatile("" ::: "memory");

        f32x4v acc2[2];
        for (int t = 0; t < 2; ++t)
            acc2[t] = (f32x4v){bias2[t], bias2[t], bias2[t], bias2[t]};
        for (int s = 0; s < 4; ++s) {
            bfrag4 a2 = *(const bfrag4*)(hrow + col * 72 + s * 16 + quad * 4);
            for (int t = 0; t < 2; ++t)
                acc2[t] = __builtin_amdgcn_mfma_f32_16x16x16bf16_1k(a2, bw2[s][t], acc2[t], 0, 0, 0);
        }
        asm volatile("" ::: "memory");

        for (int t = 0; t < 2; ++t)
            for (int r = 0; r < 4; ++r)
                z_loop[(size_t)(node0 + quad * 4 + r) * 32 + (col + 16 * t)] =
                    f2bf(acc2[t][r]);
    }
}

// ---------------- Kernel 2: edge decoder (R9 + 32-bit offsets) --------------
__global__ __launch_bounds__(256) void edge_dec_kernel(
    const int*            __restrict__ eidx,     // [2, E] int32
    const unsigned short* __restrict__ z_loop,   // [N,32] bf16
    const float*          __restrict__ dw1,      // [64,64] row-major (k,n)
    const float*          __restrict__ db1,      // [64]
    const float*          __restrict__ dw2,      // [64]
    const float*          __restrict__ db2,      // [1]
    float* __restrict__ out)                     // [E] fp32
{
    const int tid  = threadIdx.x;
    const int lane = tid & 63;
    const int quad = lane >> 4;
    const int col  = lane & 15;

    // A-frags = dw1^T tiles: aw[s][mt] holds A[m=16mt+col][k=32s+quad*8+j]
    s16x8 aw[2][4];
    float bias1[4][4];   // [mt][r] = db1[16mt + quad*4 + r]
    float w2v[4][4];     // [mt][r] = dw2[16mt + quad*4 + r]
    for (int mt = 0; mt < 4; ++mt) {
        const int h = 16 * mt + col;
        for (int s = 0; s < 2; ++s)
            for (int j = 0; j < 8; ++j)
                aw[s][mt][j] = (short)f2bf(dw1[(32 * s + quad * 8 + j) * 64 + h]);
        for (int r = 0; r < 4; ++r) {
            bias1[mt][r] = db1[16 * mt + quad * 4 + r];
            w2v[mt][r]   = dw2[16 * mt + quad * 4 + r];
        }
    }
    const float bias2 = db2[0];

    const int gwave  = blockIdx.x * 4 + (tid >> 6);
    const int nwaves = gridDim.x * 4;
    const int npairs = N_EDGES / 32;   // 100000, exact (nwaves = 8192 <= npairs)

    const unsigned qoff = (unsigned)(quad * 8);   // element offset into a row

    // prefetch indices for the first iteration (32-bit offsets; max 3.2M)
    int sA = eidx[(unsigned)(gwave * 32 + col)];
    int sB = eidx[(unsigned)(gwave * 32 + 16 + col)];
    int dA = eidx[(unsigned)(N_EDGES + gwave * 32 + col)];
    int dB = eidx[(unsigned)(N_EDGES + gwave * 32 + 16 + col)];

    for (int p = gwave; p < npairs; p += nwaves) {
        const int e0 = p * 32;

        // 4 independent 16B gathers — each IS a B-fragment
        // (B[k=quad*8+j][n=col]); 32-bit element offsets (max ~3.2M).
        s16x8 gA0 = *(const s16x8*)(z_loop + ((unsigned)sA * 32u + qoff));
        s16x8 gA1 = *(const s16x8*)(z_loop + ((unsigned)dA * 32u + qoff));
        s16x8 gB0 = *(const s16x8*)(z_loop + ((unsigned)sB * 32u + qoff));
        s16x8 gB1 = *(const s16x8*)(z_loop + ((unsigned)dB * 32u + qoff));

        // prefetch NEXT iteration's indices (branchless clamp, always valid)
        const int pn = p + nwaves;
        const int pc = pn < npairs ? pn : gwave;
        sA = eidx[(unsigned)(pc * 32 + col)];
        sB = eidx[(unsigned)(pc * 32 + 16 + col)];
        dA = eidx[(unsigned)(N_EDGES + pc * 32 + col)];
        dB = eidx[(unsigned)(N_EDGES + pc * 32 + 16 + col)];

        // he^T[m=hidden][n=edge]: 4 M-tiles x 2 K-steps per 16 edges
        f32x4v accA[4], accB[4];
        for (int mt = 0; mt < 4; ++mt) {
            f32x4v c = {bias1[mt][0], bias1[mt][1], bias1[mt][2], bias1[mt][3]};
            c = __builtin_amdgcn_mfma_f32_16x16x32_bf16(aw[0][mt], gA0, c, 0, 0, 0);
            c = __builtin_amdgcn_mfma_f32_16x16x32_bf16(aw[1][mt], gA1, c, 0, 0, 0);
            accA[mt] = c;
        }
        for (int mt = 0; mt < 4; ++mt) {
            f32x4v c = {bias1[mt][0], bias1[mt][1], bias1[mt][2], bias1[mt][3]};
            c = __builtin_amdgcn_mfma_f32_16x16x32_bf16(aw[0][mt], gB0, c, 0, 0, 0);
            c = __builtin_amdgcn_mfma_f32_16x16x32_bf16(aw[1][mt], gB1, c, 0, 0, 0);
            accB[mt] = c;
        }

        // relu + dw2-dot: lane owns 16 hidden units of ONE edge (n=col);
        // in-lane fma then 2-step quad reduce.
        float pA = 0.f, pB = 0.f;
        for (int mt = 0; mt < 4; ++mt)
            for (int r = 0; r < 4; ++r) {
                float vA = accA[mt][r]; vA = vA > 0.f ? vA : 0.f;
                float vB = accB[mt][r]; vB = vB > 0.f ? vB : 0.f;
                pA += vA * w2v[mt][r];
                pB += vB * w2v[mt][r];
            }
        pA += __shfl_xor(pA, 16, 64);
        pA += __shfl_xor(pA, 32, 64);
        pB += __shfl_xor(pB, 16, 64);
        pB += __shfl_xor(pB, 32, 64);

        // lanes 0-15: edge e0+lane (tile A); 16-31: e0+lane (tile B).
        if (lane < 32) {
            float v = (lane < 16 ? pA : pB) + bias2;
            out[(unsigned)(e0 + lane)] = v;
        }
    }
}

extern "C" void kernel_launch(void* const* d_in, const int* in_sizes, int n_in,
                              void* d_out, int out_size, void* d_ws, size_t ws_size,
                              hipStream_t stream) {
    const float* z_mod = (const float*)d_in[0];
    const int*   eidx  = (const int*)d_in[1];
    const float* w1    = (const float*)d_in[2];
    const float* b1    = (const float*)d_in[3];
    const float* w2    = (const float*)d_in[4];
    const float* b2    = (const float*)d_in[5];
    const float* dw1   = (const float*)d_in[6];
    const float* db1   = (const float*)d_in[7];
    const float* dw2   = (const float*)d_in[8];
    const float* db2   = (const float*)d_in[9];
    float*          out    = (float*)d_out;
    unsigned short* z_loop = (unsigned short*)d_ws;   // 100000*32*2B = 6.4 MB

    node_proj_kernel<<<512, 256, 0, stream>>>(z_mod, w1, b1, w2, b2, z_loop);
    // 2048 blocks = 8 blocks/CU — the residency cap at VGPR<=64, LDS=0
    edge_dec_kernel<<<2048, 256, 0, stream>>>(eidx, z_loop, dw1, db1, dw2, db2, out);
}

// Round 13
// 152.718 us; speedup vs baseline: 1.0175x; 1.0175x over previous
//
#include <hip/hip_runtime.h>

// LoopHead: node MLP (32->64->32) then edge decoder (gather/concat -> 64 -> 1)
// Wire dtypes per the reference: fp32 tensors, int32 edge_index, fp32 out.
// R13 = R9 structure with the edge GEMM moved to mfma_f32_32x32x16_bf16:
// one 32-edge tile per iteration (8 MFMAs, 2 index loads, 1 shuffle step,
// 1 coalesced store) instead of two 16-edge tiles (16/4/4/2). db1 enters as
// a persistent f32x16 C-operand (C is read-only, D distinct). Grid 1536 and
// size_t addressing exactly as R9 (best known config).

typedef short bfrag4 __attribute__((ext_vector_type(4)));   // 4 bf16 (x16 frag)
typedef short s16x8  __attribute__((ext_vector_type(8)));   // 8 bf16
typedef float f32x4v __attribute__((ext_vector_type(4)));   // fp32 x4
typedef float f32x16 __attribute__((ext_vector_type(16)));  // fp32 x16 (32x32 C/D)

#define N_NODES 100000
#define N_EDGES 3200000

__device__ __forceinline__ unsigned short f2bf(float f) {
    unsigned int i = __float_as_uint(f);
    unsigned int r = i + 0x7FFFu + ((i >> 16) & 1u);  // RNE
    return (unsigned short)(r >> 16);
}

__device__ __forceinline__ bfrag4 cvt4(float x0, float x1, float x2, float x3) {
    bfrag4 v;
    v[0] = (short)f2bf(x0);
    v[1] = (short)f2bf(x1);
    v[2] = (short)f2bf(x2);
    v[3] = (short)f2bf(x3);
    return v;
}

// ---------------- Kernel 1: node projection -> z_loop (bf16 [N,32]) --------
// (verbatim round-3/6/7/9 version — proven through all harness checks)
__global__ __launch_bounds__(256) void node_proj_kernel(
    const float* __restrict__ z_mod,   // [N,32] fp32
    const float* __restrict__ w1,      // [32,64] row-major (k,n)
    const float* __restrict__ b1,      // [64]
    const float* __restrict__ w2,      // [64,32] row-major (k,n)
    const float* __restrict__ b2,      // [32]
    unsigned short* __restrict__ z_loop)  // [N,32] bf16 out (workspace)
{
    __shared__ unsigned short hbuf[4][16 * 72];

    const int tid  = threadIdx.x;
    const int wave = tid >> 6;
    const int lane = tid & 63;
    const int quad = lane >> 4;
    const int col  = lane & 15;

    bfrag4 bw1[2][4];   // stage 1: K=32 (2 steps), N=64 (4 n-tiles)
    float  bias1[4];
    for (int t = 0; t < 4; ++t) {
        const int n = col + 16 * t;
        for (int s = 0; s < 2; ++s)
            for (int j = 0; j < 4; ++j)
                bw1[s][t][j] = (short)f2bf(w1[(s * 16 + quad * 4 + j) * 64 + n]);
        bias1[t] = b1[n];
    }
    bfrag4 bw2[4][2];   // stage 2: K=64 (4 steps), N=32 (2 n-tiles)
    float  bias2[2];
    for (int t = 0; t < 2; ++t) {
        const int n = col + 16 * t;
        for (int s = 0; s < 4; ++s)
            for (int j = 0; j < 4; ++j)
                bw2[s][t][j] = (short)f2bf(w2[(s * 16 + quad * 4 + j) * 32 + n]);
        bias2[t] = b2[n];
    }

    unsigned short* hrow = &hbuf[wave][0];

    const int gwave  = blockIdx.x * 4 + wave;
    const int nwaves = gridDim.x * 4;
    const int ntiles = N_NODES / 16;   // 6250, exact

    for (int tile = gwave; tile < ntiles; tile += nwaves) {
        const int node0 = tile * 16;
        const float* zrow = z_mod + (size_t)(node0 + col) * 32;

        f32x4v za0 = *(const f32x4v*)(zrow + 0 * 16 + quad * 4);
        f32x4v za1 = *(const f32x4v*)(zrow + 1 * 16 + quad * 4);
        bfrag4 a10 = cvt4(za0[0], za0[1], za0[2], za0[3]);
        bfrag4 a11 = cvt4(za1[0], za1[1], za1[2], za1[3]);

        f32x4v acc[4];
        for (int t = 0; t < 4; ++t) {
            f32x4v c = {bias1[t], bias1[t], bias1[t], bias1[t]};
            c = __builtin_amdgcn_mfma_f32_16x16x16bf16_1k(a10, bw1[0][t], c, 0, 0, 0);
            c = __builtin_amdgcn_mfma_f32_16x16x16bf16_1k(a11, bw1[1][t], c, 0, 0, 0);
            acc[t] = c;
        }

        for (int t = 0; t < 4; ++t)
            for (int r = 0; r < 4; ++r) {
                float v = acc[t][r];
                v = v > 0.f ? v : 0.f;
                hrow[(quad * 4 + r) * 72 + (col + 16 * t)] = f2bf(v);
            }
        asm volatile("" ::: "memory");

        f32x4v acc2[2];
        for (int t = 0; t < 2; ++t)
            acc2[t] = (f32x4v){bias2[t], bias2[t], bias2[t], bias2[t]};
        for (int s = 0; s < 4; ++s) {
            bfrag4 a2 = *(const bfrag4*)(hrow + col * 72 + s * 16 + quad * 4);
            for (int t = 0; t < 2; ++t)
                acc2[t] = __builtin_amdgcn_mfma_f32_16x16x16bf16_1k(a2, bw2[s][t], acc2[t], 0, 0, 0);
        }
        asm volatile("" ::: "memory");

        for (int t = 0; t < 2; ++t)
            for (int r = 0; r < 4; ++r)
                z_loop[(size_t)(node0 + quad * 4 + r) * 32 + (col + 16 * t)] =
                    f2bf(acc2[t][r]);
    }
}

// ---------------- Kernel 2: edge decoder (32x32x16 MFMA, 32 edges/iter) -----
__global__ __launch_bounds__(256) void edge_dec_kernel(
    const int*            __restrict__ eidx,     // [2, E] int32
    const unsigned short* __restrict__ z_loop,   // [N,32] bf16
    const float*          __restrict__ dw1,      // [64,64] row-major (k,n)
    const float*          __restrict__ db1,      // [64]
    const float*          __restrict__ dw2,      // [64]
    const float*          __restrict__ db2,      // [1]
    float* __restrict__ out)                     // [E] fp32
{
    const int tid   = threadIdx.x;
    const int lane  = tid & 63;
    const int half  = lane >> 5;    // 0/1
    const int col32 = lane & 31;    // edge-in-tile / hidden-col

    // A-frags = dw1^T tiles for 32x32x16:
    //   aw[ks][mt][j] = A[m=32mt+col32][k=16ks+8half+j] = dw1[k][h]
    s16x8 aw[4][2];
    // C/D row map (m74/m101): row = (reg&3) + 8*(reg>>2) + 4*half
    f32x16 biasC[2];     // persistent C operand: db1[32mt + row]
    float  w2v[2][16];   // dw2[32mt + row]
    for (int mt = 0; mt < 2; ++mt) {
        const int h = 32 * mt + col32;
        for (int ks = 0; ks < 4; ++ks)
            for (int j = 0; j < 8; ++j)
                aw[ks][mt][j] = (short)f2bf(dw1[(16 * ks + 8 * half + j) * 64 + h]);
        for (int reg = 0; reg < 16; ++reg) {
            const int row = (reg & 3) + 8 * (reg >> 2) + 4 * half;
            biasC[mt][reg] = db1[32 * mt + row];
            w2v[mt][reg]   = dw2[32 * mt + row];
        }
    }
    const float bias2 = db2[0];

    const int gwave  = blockIdx.x * 4 + (tid >> 6);
    const int nwaves = gridDim.x * 4;
    const int ntil   = N_EDGES / 32;   // 100000, exact (nwaves = 6144 <= ntil)

    // prefetch indices for the first iteration
    int sE = eidx[gwave * 32 + col32];
    int dE = eidx[N_EDGES + gwave * 32 + col32];

    for (int p = gwave; p < ntil; p += nwaves) {
        const int e0 = p * 32;

        // 4 gathers = the 4 B-fragments (B[k=8half+j][n=col32]):
        //   ks0: src feats 0..15  (lane half-split)   ks1: src feats 16..31
        //   ks2: dst feats 0..15                      ks3: dst feats 16..31
        const unsigned short* zs = z_loop + (size_t)sE * 32 + half * 8;
        const unsigned short* zd = z_loop + (size_t)dE * 32 + half * 8;
        s16x8 g0a = *(const s16x8*)(zs);
        s16x8 g0b = *(const s16x8*)(zs + 16);
        s16x8 g1a = *(const s16x8*)(zd);
        s16x8 g1b = *(const s16x8*)(zd + 16);

        // prefetch NEXT iteration's indices (branchless clamp, always valid)
        const int pn = p + nwaves;
        const int pc = pn < ntil ? pn : gwave;
        sE = eidx[pc * 32 + col32];
        dE = eidx[N_EDGES + pc * 32 + col32];

        // He^T[m=hidden 64][n=edge 32] in 2 M-tiles; biasC is the read-only C
        f32x16 acc0, acc1;
        {
            f32x16 c = __builtin_amdgcn_mfma_f32_32x32x16_bf16(aw[0][0], g0a, biasC[0], 0, 0, 0);
            c = __builtin_amdgcn_mfma_f32_32x32x16_bf16(aw[1][0], g0b, c, 0, 0, 0);
            c = __builtin_amdgcn_mfma_f32_32x32x16_bf16(aw[2][0], g1a, c, 0, 0, 0);
            acc0 = __builtin_amdgcn_mfma_f32_32x32x16_bf16(aw[3][0], g1b, c, 0, 0, 0);
        }
        {
            f32x16 c = __builtin_amdgcn_mfma_f32_32x32x16_bf16(aw[0][1], g0a, biasC[1], 0, 0, 0);
            c = __builtin_amdgcn_mfma_f32_32x32x16_bf16(aw[1][1], g0b, c, 0, 0, 0);
            c = __builtin_amdgcn_mfma_f32_32x32x16_bf16(aw[2][1], g1a, c, 0, 0, 0);
            acc1 = __builtin_amdgcn_mfma_f32_32x32x16_bf16(aw[3][1], g1b, c, 0, 0, 0);
        }

        // relu + dw2-dot: lane holds 32 of edge col32's 64 hidden units
        // (rows per the C/D map); partner lane (xor 32) holds the other 32.
        float pv = 0.f;
        for (int reg = 0; reg < 16; ++reg) {
            float v0 = acc0[reg]; v0 = v0 > 0.f ? v0 : 0.f;
            float v1 = acc1[reg]; v1 = v1 > 0.f ? v1 : 0.f;
            pv += v0 * w2v[0][reg];
            pv += v1 * w2v[1][reg];
        }
        pv += __shfl_xor(pv, 32, 64);   // single reduce step

        // lanes 0-31 store 32 consecutive edges: one coalesced 128B store
        if (lane < 32)
            out[e0 + lane] = pv + bias2;
    }
}

extern "C" void kernel_launch(void* const* d_in, const int* in_sizes, int n_in,
                              void* d_out, int out_size, void* d_ws, size_t ws_size,
                              hipStream_t stream) {
    const float* z_mod = (const float*)d_in[0];
    const int*   eidx  = (const int*)d_in[1];
    const float* w1    = (const float*)d_in[2];
    const float* b1    = (const float*)d_in[3];
    const float* w2    = (const float*)d_in[4];
    const float* b2    = (const float*)d_in[5];
    const float* dw1   = (const float*)d_in[6];
    const float* db1   = (const float*)d_in[7];
    const float* dw2   = (const float*)d_in[8];
    const float* db2   = (const float*)d_in[9];
    float*          out    = (float*)d_out;
    unsigned short* z_loop = (unsigned short*)d_ws;   // 100000*32*2B = 6.4 MB

    node_proj_kernel<<<512, 256, 0, stream>>>(z_mod, w1, b1, w2, b2, z_loop);
    edge_dec_kernel<<<1536, 256, 0, stream>>>(eidx, z_loop, dw1, db1, dw2, db2, out);
}